// Round 4
// baseline (321.218 us; speedup 1.0000x reference)
//
#include <hip/hip_runtime.h>

typedef unsigned int u32;
typedef unsigned long long u64;

#define NB 10
#define BLOCKS 2048       // 8 blocks/CU, all co-resident -> 32 waves/CU
#define TPB 256           // 4 waves
#define F4_PER_BLOCK 4096 // 16384 elems/block, contiguous
// per thread: 16 float4 iters at stride 256 f4 (4 KB), block walk contiguous

// ws layout: bin b owns cache line at u32 index 32*b:
//   [32b+0..1] u64 sum(ffx), [32b+2] count, [32b+3] positives
__global__ void rd_zero_ws(u32* __restrict__ ws) {
    if (threadIdx.x < 320) ws[threadIdx.x] = 0u;
}

// Per element: sigmoid -> bin -> 4 packed u64 register accumulators.
// 6-bit count/pos fields; 12-bit conf-frac fields (7-bit fixed point),
// unpack window 32 elems: 32*127 = 4064 < 4095 (field-safe).
__device__ __forceinline__ void rd_acc(float x, int lab,
                                       u64& c64, u64& p64, u64& flo, u64& fhi) {
    float e = __expf(-x);
    float conf = __builtin_amdgcn_rcpf(1.0f + e);        // sigmoid
    float t10 = __builtin_fmaf(conf, 10.0f, -1e-6f);     // bins are (l,u]
    int b = min(9, (int)t10);
    float frac = t10 - (float)b;                         // [0,1)
    u32 ffx = (u32)__builtin_fmaf(frac, 127.0f, 0.5f);   // 7-bit fixed point

    u32 sh6 = (u32)(b * 6);
    c64 += 1ull << sh6;                                  // 6-bit count fields
    p64 += ((u64)(u32)lab) << sh6;                       // 6-bit positive fields

    bool lo = b < 5;
    u32 sh12 = (u32)(b * 12);
    u32 shf = lo ? sh12 : (sh12 - 60u);
    u64 v = ((u64)ffx) << shf;                           // 12-bit fields, 5 per u64
    flo += lo ? v : 0ull;
    fhi += lo ? 0ull : v;
}

__device__ __forceinline__ void rd_acc4(const float4& x, const int4& y,
                                        u64& c64, u64& p64, u64& flo, u64& fhi) {
    rd_acc(x.x, y.x, c64, p64, flo, fhi);
    rd_acc(x.y, y.y, c64, p64, flo, fhi);
    rd_acc(x.z, y.z, c64, p64, flo, fhi);
    rd_acc(x.w, y.w, c64, p64, flo, fhi);
}

// m146-regime streaming: plain vectorized loads, contiguous block segments,
// maximum TLP. __launch_bounds__(256, 8) forces VGPR <= 64 so all 8 blocks/CU
// (32 waves/CU) are resident — latency hiding comes from wave count, not from
// source-level pipelining (which the compiler dissolves anyway, r1/r3).
__global__ __launch_bounds__(TPB, 8) void rd_hist(const float* __restrict__ logits,
                                                  const int* __restrict__ labels,
                                                  u32* __restrict__ ws,
                                                  long long n) {
    u32 cp[NB], cf[NB];
    #pragma unroll
    for (int b = 0; b < NB; ++b) { cp[b] = 0u; cf[b] = 0u; }

    u64 c64 = 0, p64 = 0, flo = 0, fhi = 0;

    #define UNPACK() do {                                                   \
        _Pragma("unroll")                                                   \
        for (int b = 0; b < NB; ++b) {                                      \
            u32 cnt = (u32)(c64 >> (6 * b)) & 63u;                          \
            u32 pos = (u32)(p64 >> (6 * b)) & 63u;                          \
            cp[b] += cnt | (pos << 16);                                     \
            cf[b] += (b < 5) ? ((u32)(flo >> (12 * b)) & 4095u)             \
                             : ((u32)(fhi >> (12 * (b - 5))) & 4095u);      \
        }                                                                   \
        c64 = 0; p64 = 0; flo = 0; fhi = 0;                                 \
    } while (0)

    long long nf4 = n >> 2;
    long long segll = (long long)blockIdx.x * F4_PER_BLOCK;

    if (segll + F4_PER_BLOCK <= nf4) {
        // 32-bit offsets: max f4 index ~8.4M, fits easily
        int seg = (int)segll + (int)threadIdx.x;
        const float4* gl = (const float4*)logits + seg;
        const int4*   gi = (const int4*)labels + seg;

        #pragma unroll
        for (int h = 0; h < 2; ++h) {        // 2 windows x 32 elems
            #pragma unroll
            for (int g = 0; g < 4; ++g) {    // 4 groups x 2 float4-pairs
                const int k = (h * 8 + g * 2) * 256;
                float4 x0 = gl[k];
                int4   y0 = gi[k];
                float4 x1 = gl[k + 256];
                int4   y1 = gi[k + 256];
                rd_acc4(x0, y0, c64, p64, flo, fhi);
                rd_acc4(x1, y1, c64, p64, flo, fhi);
            }
            UNPACK();
        }
    }

    // generic tail (empty at N=2^25: 2048*16384 covers exactly)
    long long done_f4 = ((long long)gridDim.x < nf4 / F4_PER_BLOCK
                             ? (long long)gridDim.x
                             : nf4 / F4_PER_BLOCK) * F4_PER_BLOCK;
    long long tail = done_f4 * 4;
    if (tail < n) {
        long long tid    = (long long)blockIdx.x * blockDim.x + threadIdx.x;
        long long stride = (long long)gridDim.x * blockDim.x;
        for (long long i = tail + tid; i < n; i += stride) {
            float e = __expf(-logits[i]);
            float conf = __builtin_amdgcn_rcpf(1.0f + e);
            float t10 = __builtin_fmaf(conf, 10.0f, -1e-6f);
            int b = min(9, (int)t10);
            float frac = t10 - (float)b;
            u32 ffx = (u32)__builtin_fmaf(frac, 127.0f, 0.5f);
            atomicAdd((u64*)&ws[32 * b], (u64)ffx);
            atomicAdd(&ws[32 * b + 2], 1u);
            atomicAdd(&ws[32 * b + 3], (u32)labels[i]);
        }
    }
    #undef UNPACK

    // wave reduce + block combine (LDS: 320 B total)
    __shared__ u32 s_cp[4][NB];
    __shared__ u32 s_cf[4][NB];
    int lane = threadIdx.x & 63;
    int wave = threadIdx.x >> 6;
    #pragma unroll
    for (int b = 0; b < NB; ++b) {
        u32 c = cp[b];                  // per-thread count <= 64 -> 16-bit safe
        u32 f = cf[b];
        #pragma unroll
        for (int off = 32; off; off >>= 1) {
            c += __shfl_down(c, off, 64);
            f += __shfl_down(f, off, 64);
        }
        if (lane == 0) { s_cp[wave][b] = c; s_cf[wave][b] = f; }
    }
    __syncthreads();

    if (threadIdx.x < NB) {
        int b = threadIdx.x;
        u32 c = s_cp[0][b] + s_cp[1][b] + s_cp[2][b] + s_cp[3][b];  // <= 16384
        u64 f = (u64)s_cf[0][b] + s_cf[1][b] + s_cf[2][b] + s_cf[3][b];
        atomicAdd((u64*)&ws[32 * b], f);
        atomicAdd(&ws[32 * b + 2], c & 0xFFFFu);
        atomicAdd(&ws[32 * b + 3], c >> 16);
    }
}

__global__ void rd_finalize(const u32* __restrict__ ws, float* __restrict__ out) {
    int b = threadIdx.x;
    if (b < NB) {
        u64 f   = *(const u64*)&ws[32 * b];
        u32 cnt = ws[32 * b + 2];
        u32 pos = ws[32 * b + 3];
        double sumconf = ((double)b * (double)cnt + (double)f * (1.0 / 127.0)) * 0.1;
        float denom = fmaxf((float)cnt, 1.0f);
        bool ne = cnt > 0u;
        out[b]      = ne ? ((float)pos / denom) : 0.0f;
        out[NB + b] = ne ? (float)(sumconf / (double)denom) : 0.0f;
    }
}

extern "C" void kernel_launch(void* const* d_in, const int* in_sizes, int n_in,
                              void* d_out, int out_size, void* d_ws, size_t ws_size,
                              hipStream_t stream) {
    const float* logits = (const float*)d_in[0];
    const int*   labels = (const int*)d_in[1];
    float* out = (float*)d_out;
    u32*   ws  = (u32*)d_ws;
    long long n = (long long)in_sizes[0];

    rd_zero_ws<<<1, 512, 0, stream>>>(ws);
    rd_hist<<<BLOCKS, TPB, 0, stream>>>(logits, labels, ws, n);
    rd_finalize<<<1, 64, 0, stream>>>(ws, out);
}

// Round 7
// 287.336 us; speedup vs baseline: 1.1179x; 1.1179x over previous
//
#include <hip/hip_runtime.h>

typedef unsigned int u32;
typedef unsigned long long u64;

#define NB 10
#define BLOCKS 1024       // 4 blocks/CU -> one generation, all resident
#define TPB 256           // 4 waves
#define ITERS 32          // float4 batches per thread
#define DEPTH 4           // register pipeline depth (batches in flight)
#define WAVE_F4 (ITERS * 64)   // 2048 contiguous float4 per wave

// ws layout: bin b owns cache line at u32 index 32*b:
//   [32b+0..1] u64 sum(ffx), [32b+2] count, [32b+3] positives
__global__ void rd_zero_ws(u32* __restrict__ ws) {
    if (threadIdx.x < 320) ws[threadIdx.x] = 0u;
}

// Non-temporal int4 load via 4 scalar nt dword loads (clang merges adjacent
// nt loads into global_load_dwordx4 nt). Labels get no L3 allocation.
__device__ __forceinline__ int4 nt_load_i4(const int4* p) {
    const int* q = (const int*)p;
    int4 r;
    r.x = __builtin_nontemporal_load(q);
    r.y = __builtin_nontemporal_load(q + 1);
    r.z = __builtin_nontemporal_load(q + 2);
    r.w = __builtin_nontemporal_load(q + 3);
    return r;
}

// Per element: sigmoid -> bin -> 4 packed u64 register accumulators.
// 6-bit count/pos fields; 12-bit conf-frac fields (7-bit fixed point),
// unpack window 32 elems: 32*127 = 4064 < 4095 (field-safe).
__device__ __forceinline__ void rd_acc(float x, int lab,
                                       u64& c64, u64& p64, u64& flo, u64& fhi) {
    float e = __expf(-x);
    float conf = __builtin_amdgcn_rcpf(1.0f + e);        // sigmoid
    float t10 = __builtin_fmaf(conf, 10.0f, -1e-6f);     // bins are (l,u]
    int b = min(9, (int)t10);
    float frac = t10 - (float)b;                         // [0,1)
    u32 ffx = (u32)__builtin_fmaf(frac, 127.0f, 0.5f);   // 7-bit fixed point

    u32 sh6 = (u32)(b * 6);
    c64 += 1ull << sh6;                                  // 6-bit count fields
    p64 += ((u64)(u32)lab) << sh6;                       // 6-bit positive fields

    bool lo = b < 5;
    u32 sh12 = (u32)(b * 12);
    u32 shf = lo ? sh12 : (sh12 - 60u);
    u64 v = ((u64)ffx) << shf;                           // 12-bit fields, 5 per u64
    flo += lo ? v : 0ull;
    fhi += lo ? 0ull : v;
}

__device__ __forceinline__ void rd_acc4(const float4& x, const int4& y,
                                        u64& c64, u64& p64, u64& flo, u64& fhi) {
    rd_acc(x.x, y.x, c64, p64, flo, fhi);
    rd_acc(x.y, y.y, c64, p64, flo, fhi);
    rd_acc(x.z, y.z, c64, p64, flo, fhi);
    rd_acc(x.w, y.w, c64, p64, flo, fhi);
}

// r3 structure (best so far: 117 us, 2.29 TB/s effective read BW) with ONE
// change: label loads are non-temporal (no L3 allocation). Working set is
// 268 MB vs 256 MB L3 -> capacity thrash; FETCH_SIZE 134 MB = exactly one
// array's worth reaches HBM each dispatch. Keeping labels out of L3 lets
// the 134 MB logits array become fully L3-resident (cache partitioning
// instead of LRU thrash); labels stream from HBM (~21 us of HBM time).
__global__ __launch_bounds__(TPB, 4) void rd_hist(const float* __restrict__ logits,
                                                  const int* __restrict__ labels,
                                                  u32* __restrict__ ws,
                                                  long long n) {
    u32 cp[NB], cf[NB];
    #pragma unroll
    for (int b = 0; b < NB; ++b) { cp[b] = 0u; cf[b] = 0u; }

    const float4* l4 = (const float4*)logits;
    const int4*   i4 = (const int4*)labels;
    int lane = threadIdx.x & 63;
    int wave = threadIdx.x >> 6;
    long long nf4 = n >> 2;
    long long seg = (long long)blockIdx.x * (4 * WAVE_F4);

    u64 c64 = 0, p64 = 0, flo = 0, fhi = 0;

    #define UNPACK() do {                                                   \
        _Pragma("unroll")                                                   \
        for (int b = 0; b < NB; ++b) {                                      \
            u32 cnt = (u32)(c64 >> (6 * b)) & 63u;                          \
            u32 pos = (u32)(p64 >> (6 * b)) & 63u;                          \
            cp[b] += cnt | (pos << 16);                                     \
            cf[b] += (b < 5) ? ((u32)(flo >> (12 * b)) & 4095u)             \
                             : ((u32)(fhi >> (12 * (b - 5))) & 4095u);      \
        }                                                                   \
        c64 = 0; p64 = 0; flo = 0; fhi = 0;                                 \
    } while (0)

    if (seg + 4 * WAVE_F4 <= nf4) {
        long long gb = seg + (long long)wave * WAVE_F4;
        const float4* gl = l4 + gb + lane;
        const int4*   gi = i4 + gb + lane;

        // prologue: fill the ring (4 batches = 8 independent 16 B loads)
        float4 px0 = gl[0 * 64], px1 = gl[1 * 64], px2 = gl[2 * 64], px3 = gl[3 * 64];
        int4 py0 = nt_load_i4(gi + 0 * 64);
        int4 py1 = nt_load_i4(gi + 1 * 64);
        int4 py2 = nt_load_i4(gi + 2 * 64);
        int4 py3 = nt_load_i4(gi + 3 * 64);

        #pragma unroll
        for (int t = 0; t < ITERS; ++t) {
            const int s = t & 3;            // static after unroll
            float4 x; int4 y;
            if      (s == 0) { x = px0; y = py0; }
            else if (s == 1) { x = px1; y = py1; }
            else if (s == 2) { x = px2; y = py2; }
            else             { x = px3; y = py3; }
            if (t + DEPTH < ITERS) {        // refill freed slot BEFORE compute
                if      (s == 0) { px0 = gl[(t + DEPTH) * 64];
                                   py0 = nt_load_i4(gi + (t + DEPTH) * 64); }
                else if (s == 1) { px1 = gl[(t + DEPTH) * 64];
                                   py1 = nt_load_i4(gi + (t + DEPTH) * 64); }
                else if (s == 2) { px2 = gl[(t + DEPTH) * 64];
                                   py2 = nt_load_i4(gi + (t + DEPTH) * 64); }
                else             { px3 = gl[(t + DEPTH) * 64];
                                   py3 = nt_load_i4(gi + (t + DEPTH) * 64); }
            }
            rd_acc4(x, y, c64, p64, flo, fhi);
            if ((t & 7) == 7) UNPACK();     // every 32 elems, field-safe
        }
    }

    // generic tail (empty at N=2^25): direct atomics, rarely runs
    long long done_f4 = ((long long)gridDim.x < nf4 / (4 * WAVE_F4)
                             ? (long long)gridDim.x
                             : nf4 / (4 * WAVE_F4)) * (4 * WAVE_F4);
    long long tail = done_f4 * 4;
    if (tail < n) {
        long long tid    = (long long)blockIdx.x * blockDim.x + threadIdx.x;
        long long stride = (long long)gridDim.x * blockDim.x;
        for (long long i = tail + tid; i < n; i += stride) {
            float e = __expf(-logits[i]);
            float conf = __builtin_amdgcn_rcpf(1.0f + e);
            float t10 = __builtin_fmaf(conf, 10.0f, -1e-6f);
            int b = min(9, (int)t10);
            float frac = t10 - (float)b;
            u32 ffx = (u32)__builtin_fmaf(frac, 127.0f, 0.5f);
            atomicAdd((u64*)&ws[32 * b], (u64)ffx);
            atomicAdd(&ws[32 * b + 2], 1u);
            atomicAdd(&ws[32 * b + 3], (u32)labels[i]);
        }
    }
    #undef UNPACK

    // wave reduce + block combine (LDS: 320 B total)
    __shared__ u32 s_cp[4][NB];
    __shared__ u32 s_cf[4][NB];
    #pragma unroll
    for (int b = 0; b < NB; ++b) {
        u32 c = cp[b];                  // per-thread count <= 128 -> 16-bit safe
        u32 f = cf[b];
        #pragma unroll
        for (int off = 32; off; off >>= 1) {
            c += __shfl_down(c, off, 64);
            f += __shfl_down(f, off, 64);
        }
        if (lane == 0) { s_cp[wave][b] = c; s_cf[wave][b] = f; }
    }
    __syncthreads();

    if (threadIdx.x < NB) {
        int b = threadIdx.x;
        u32 c = s_cp[0][b] + s_cp[1][b] + s_cp[2][b] + s_cp[3][b];
        u64 f = (u64)s_cf[0][b] + s_cf[1][b] + s_cf[2][b] + s_cf[3][b];
        atomicAdd((u64*)&ws[32 * b], f);
        atomicAdd(&ws[32 * b + 2], c & 0xFFFFu);
        atomicAdd(&ws[32 * b + 3], c >> 16);
    }
}

__global__ void rd_finalize(const u32* __restrict__ ws, float* __restrict__ out) {
    int b = threadIdx.x;
    if (b < NB) {
        u64 f   = *(const u64*)&ws[32 * b];
        u32 cnt = ws[32 * b + 2];
        u32 pos = ws[32 * b + 3];
        double sumconf = ((double)b * (double)cnt + (double)f * (1.0 / 127.0)) * 0.1;
        float denom = fmaxf((float)cnt, 1.0f);
        bool ne = cnt > 0u;
        out[b]      = ne ? ((float)pos / denom) : 0.0f;
        out[NB + b] = ne ? (float)(sumconf / (double)denom) : 0.0f;
    }
}

extern "C" void kernel_launch(void* const* d_in, const int* in_sizes, int n_in,
                              void* d_out, int out_size, void* d_ws, size_t ws_size,
                              hipStream_t stream) {
    const float* logits = (const float*)d_in[0];
    const int*   labels = (const int*)d_in[1];
    float* out = (float*)d_out;
    u32*   ws  = (u32*)d_ws;
    long long n = (long long)in_sizes[0];

    rd_zero_ws<<<1, 512, 0, stream>>>(ws);
    rd_hist<<<BLOCKS, TPB, 0, stream>>>(logits, labels, ws, n);
    rd_finalize<<<1, 64, 0, stream>>>(ws, out);
}

// Round 8
// 277.859 us; speedup vs baseline: 1.1560x; 1.0341x over previous
//
#include <hip/hip_runtime.h>

typedef unsigned int u32;
typedef unsigned long long u64;

#define NB 10
#define BLOCKS 1024       // 4 blocks/CU -> one generation, all resident
#define TPB 256           // 4 waves
#define ITERS 32          // float4 batches per thread
#define DEPTH 4           // register pipeline depth (batches in flight)
#define WAVE_F4 (ITERS * 64)   // 2048 contiguous float4 per wave

// ws layout: bin b owns cache line at u32 index 32*b:
//   [32b+0..1] u64 sum(ffx), [32b+2] count, [32b+3] positives
__global__ void rd_zero_ws(u32* __restrict__ ws) {
    if (threadIdx.x < 320) ws[threadIdx.x] = 0u;
}

// Non-temporal 16 B loads via 4 scalar nt dword loads (clang merges adjacent
// nt loads into global_load_dwordx4 nt). Streamed data gets no cache alloc.
__device__ __forceinline__ int4 nt_load_i4(const int4* p) {
    const int* q = (const int*)p;
    int4 r;
    r.x = __builtin_nontemporal_load(q);
    r.y = __builtin_nontemporal_load(q + 1);
    r.z = __builtin_nontemporal_load(q + 2);
    r.w = __builtin_nontemporal_load(q + 3);
    return r;
}

__device__ __forceinline__ float4 nt_load_f4(const float4* p) {
    const float* q = (const float*)p;
    float4 r;
    r.x = __builtin_nontemporal_load(q);
    r.y = __builtin_nontemporal_load(q + 1);
    r.z = __builtin_nontemporal_load(q + 2);
    r.w = __builtin_nontemporal_load(q + 3);
    return r;
}

// Per element: sigmoid -> bin -> 4 packed u64 register accumulators.
// 6-bit count/pos fields; 12-bit conf-frac fields (7-bit fixed point),
// unpack window 32 elems: 32*127 = 4064 < 4095 (field-safe).
__device__ __forceinline__ void rd_acc(float x, int lab,
                                       u64& c64, u64& p64, u64& flo, u64& fhi) {
    float e = __expf(-x);
    float conf = __builtin_amdgcn_rcpf(1.0f + e);        // sigmoid
    float t10 = __builtin_fmaf(conf, 10.0f, -1e-6f);     // bins are (l,u]
    int b = min(9, (int)t10);
    float frac = t10 - (float)b;                         // [0,1)
    u32 ffx = (u32)__builtin_fmaf(frac, 127.0f, 0.5f);   // 7-bit fixed point

    u32 sh6 = (u32)(b * 6);
    c64 += 1ull << sh6;                                  // 6-bit count fields
    p64 += ((u64)(u32)lab) << sh6;                       // 6-bit positive fields

    bool lo = b < 5;
    u32 sh12 = (u32)(b * 12);
    u32 shf = lo ? sh12 : (sh12 - 60u);
    u64 v = ((u64)ffx) << shf;                           // 12-bit fields, 5 per u64
    flo += lo ? v : 0ull;
    fhi += lo ? 0ull : v;
}

__device__ __forceinline__ void rd_acc4(const float4& x, const int4& y,
                                        u64& c64, u64& p64, u64& flo, u64& fhi) {
    rd_acc(x.x, y.x, c64, p64, flo, fhi);
    rd_acc(x.y, y.y, c64, p64, flo, fhi);
    rd_acc(x.z, y.z, c64, p64, flo, fhi);
    rd_acc(x.w, y.w, c64, p64, flo, fhi);
}

// r7 (labels-nt: 97 us, 2.77 TB/s) with ONE change: logits loads are ALSO
// non-temporal. Theory: streaming data with zero reuse that allocates in
// L2/L3 throttles the stream via fill/evict machinery (labels-nt removed
// half that pressure -> +20%). Full-nt removes the rest; even if logits
// lose L3 residency, the all-HBM floor is 268 MB / 6.3 TB/s = 43 us.
__global__ __launch_bounds__(TPB, 4) void rd_hist(const float* __restrict__ logits,
                                                  const int* __restrict__ labels,
                                                  u32* __restrict__ ws,
                                                  long long n) {
    u32 cp[NB], cf[NB];
    #pragma unroll
    for (int b = 0; b < NB; ++b) { cp[b] = 0u; cf[b] = 0u; }

    const float4* l4 = (const float4*)logits;
    const int4*   i4 = (const int4*)labels;
    int lane = threadIdx.x & 63;
    int wave = threadIdx.x >> 6;
    long long nf4 = n >> 2;
    long long seg = (long long)blockIdx.x * (4 * WAVE_F4);

    u64 c64 = 0, p64 = 0, flo = 0, fhi = 0;

    #define UNPACK() do {                                                   \
        _Pragma("unroll")                                                   \
        for (int b = 0; b < NB; ++b) {                                      \
            u32 cnt = (u32)(c64 >> (6 * b)) & 63u;                          \
            u32 pos = (u32)(p64 >> (6 * b)) & 63u;                          \
            cp[b] += cnt | (pos << 16);                                     \
            cf[b] += (b < 5) ? ((u32)(flo >> (12 * b)) & 4095u)             \
                             : ((u32)(fhi >> (12 * (b - 5))) & 4095u);      \
        }                                                                   \
        c64 = 0; p64 = 0; flo = 0; fhi = 0;                                 \
    } while (0)

    if (seg + 4 * WAVE_F4 <= nf4) {
        long long gb = seg + (long long)wave * WAVE_F4;
        const float4* gl = l4 + gb + lane;
        const int4*   gi = i4 + gb + lane;

        // prologue: fill the ring (4 batches = 8 independent 16 B loads)
        float4 px0 = nt_load_f4(gl + 0 * 64);
        float4 px1 = nt_load_f4(gl + 1 * 64);
        float4 px2 = nt_load_f4(gl + 2 * 64);
        float4 px3 = nt_load_f4(gl + 3 * 64);
        int4 py0 = nt_load_i4(gi + 0 * 64);
        int4 py1 = nt_load_i4(gi + 1 * 64);
        int4 py2 = nt_load_i4(gi + 2 * 64);
        int4 py3 = nt_load_i4(gi + 3 * 64);

        #pragma unroll
        for (int t = 0; t < ITERS; ++t) {
            const int s = t & 3;            // static after unroll
            float4 x; int4 y;
            if      (s == 0) { x = px0; y = py0; }
            else if (s == 1) { x = px1; y = py1; }
            else if (s == 2) { x = px2; y = py2; }
            else             { x = px3; y = py3; }
            if (t + DEPTH < ITERS) {        // refill freed slot BEFORE compute
                if      (s == 0) { px0 = nt_load_f4(gl + (t + DEPTH) * 64);
                                   py0 = nt_load_i4(gi + (t + DEPTH) * 64); }
                else if (s == 1) { px1 = nt_load_f4(gl + (t + DEPTH) * 64);
                                   py1 = nt_load_i4(gi + (t + DEPTH) * 64); }
                else if (s == 2) { px2 = nt_load_f4(gl + (t + DEPTH) * 64);
                                   py2 = nt_load_i4(gi + (t + DEPTH) * 64); }
                else             { px3 = nt_load_f4(gl + (t + DEPTH) * 64);
                                   py3 = nt_load_i4(gi + (t + DEPTH) * 64); }
            }
            rd_acc4(x, y, c64, p64, flo, fhi);
            if ((t & 7) == 7) UNPACK();     // every 32 elems, field-safe
        }
    }

    // generic tail (empty at N=2^25): direct atomics, rarely runs
    long long done_f4 = ((long long)gridDim.x < nf4 / (4 * WAVE_F4)
                             ? (long long)gridDim.x
                             : nf4 / (4 * WAVE_F4)) * (4 * WAVE_F4);
    long long tail = done_f4 * 4;
    if (tail < n) {
        long long tid    = (long long)blockIdx.x * blockDim.x + threadIdx.x;
        long long stride = (long long)gridDim.x * blockDim.x;
        for (long long i = tail + tid; i < n; i += stride) {
            float e = __expf(-logits[i]);
            float conf = __builtin_amdgcn_rcpf(1.0f + e);
            float t10 = __builtin_fmaf(conf, 10.0f, -1e-6f);
            int b = min(9, (int)t10);
            float frac = t10 - (float)b;
            u32 ffx = (u32)__builtin_fmaf(frac, 127.0f, 0.5f);
            atomicAdd((u64*)&ws[32 * b], (u64)ffx);
            atomicAdd(&ws[32 * b + 2], 1u);
            atomicAdd(&ws[32 * b + 3], (u32)labels[i]);
        }
    }
    #undef UNPACK

    // wave reduce + block combine (LDS: 320 B total)
    __shared__ u32 s_cp[4][NB];
    __shared__ u32 s_cf[4][NB];
    #pragma unroll
    for (int b = 0; b < NB; ++b) {
        u32 c = cp[b];                  // per-thread count <= 128 -> 16-bit safe
        u32 f = cf[b];
        #pragma unroll
        for (int off = 32; off; off >>= 1) {
            c += __shfl_down(c, off, 64);
            f += __shfl_down(f, off, 64);
        }
        if (lane == 0) { s_cp[wave][b] = c; s_cf[wave][b] = f; }
    }
    __syncthreads();

    if (threadIdx.x < NB) {
        int b = threadIdx.x;
        u32 c = s_cp[0][b] + s_cp[1][b] + s_cp[2][b] + s_cp[3][b];
        u64 f = (u64)s_cf[0][b] + s_cf[1][b] + s_cf[2][b] + s_cf[3][b];
        atomicAdd((u64*)&ws[32 * b], f);
        atomicAdd(&ws[32 * b + 2], c & 0xFFFFu);
        atomicAdd(&ws[32 * b + 3], c >> 16);
    }
}

__global__ void rd_finalize(const u32* __restrict__ ws, float* __restrict__ out) {
    int b = threadIdx.x;
    if (b < NB) {
        u64 f   = *(const u64*)&ws[32 * b];
        u32 cnt = ws[32 * b + 2];
        u32 pos = ws[32 * b + 3];
        double sumconf = ((double)b * (double)cnt + (double)f * (1.0 / 127.0)) * 0.1;
        float denom = fmaxf((float)cnt, 1.0f);
        bool ne = cnt > 0u;
        out[b]      = ne ? ((float)pos / denom) : 0.0f;
        out[NB + b] = ne ? (float)(sumconf / (double)denom) : 0.0f;
    }
}

extern "C" void kernel_launch(void* const* d_in, const int* in_sizes, int n_in,
                              void* d_out, int out_size, void* d_ws, size_t ws_size,
                              hipStream_t stream) {
    const float* logits = (const float*)d_in[0];
    const int*   labels = (const int*)d_in[1];
    float* out = (float*)d_out;
    u32*   ws  = (u32*)d_ws;
    long long n = (long long)in_sizes[0];

    rd_zero_ws<<<1, 512, 0, stream>>>(ws);
    rd_hist<<<BLOCKS, TPB, 0, stream>>>(logits, labels, ws, n);
    rd_finalize<<<1, 64, 0, stream>>>(ws, out);
}